// Round 1
// baseline (2499.619 us; speedup 1.0000x reference)
//
#include <hip/hip_runtime.h>
#include <hip/hip_bf16.h>
#include <cstdint>

// Decoder cell: B=2, S=T=2048, D=1024, H=16, HD=64. All fp32.
// Baseline: fp32 vector-ALU tiled GEMM + fp32 flash attention + LN.

#define D_DIM 1024
#define SEQ   2048
#define NHEAD 16
#define HDIM  64
#define MROWS 4096   // B*S = B*T

// ---------------------------------------------------------------------------
// GEMM: C[M,N] = A[M,K] @ W[K,N] + bias[N] (+ resid[M,N])   K=N=1024, M=4096
// 64x64 tile, BK=16, 256 threads, 4x4 microtile/thread.
// ---------------------------------------------------------------------------
__global__ __launch_bounds__(256) void gemm_bias_kernel(
    const float* __restrict__ A, const float* __restrict__ W,
    const float* __restrict__ bias, const float* __restrict__ resid,
    float* __restrict__ C)
{
    const int K = D_DIM, N = D_DIM;
    __shared__ float As[16][68];   // [k][m]
    __shared__ float Bs[16][68];   // [k][n]
    const int t  = threadIdx.x;
    const int tx = t & 15, ty = t >> 4;
    const int bm = blockIdx.x, bn = blockIdx.y;

    // staging indices
    const int arow = t >> 2;          // 0..63
    const int akq  = (t & 3) << 2;    // 0,4,8,12
    const int bkr  = t >> 4;          // 0..15
    const int bnq  = (t & 15) << 2;   // 0..60

    const float* Aptr = A + (size_t)(bm * 64 + arow) * K + akq;
    const float* Wptr = W + (size_t)bkr * N + bn * 64 + bnq;

    float acc[4][4] = {};

    float4 av = *(const float4*)Aptr;
    float4 wv = *(const float4*)Wptr;

    for (int k0 = 0; k0 < K; k0 += 16) {
        __syncthreads();
        As[akq + 0][arow] = av.x;
        As[akq + 1][arow] = av.y;
        As[akq + 2][arow] = av.z;
        As[akq + 3][arow] = av.w;
        *(float4*)&Bs[bkr][bnq] = wv;
        __syncthreads();
        if (k0 + 16 < K) {
            av = *(const float4*)(Aptr + (k0 + 16));
            wv = *(const float4*)(Wptr + (size_t)(k0 + 16) * N);
        }
        #pragma unroll
        for (int kk = 0; kk < 16; ++kk) {
            float4 a = *(const float4*)&As[kk][ty << 2];
            float4 b = *(const float4*)&Bs[kk][tx << 2];
            acc[0][0] += a.x * b.x; acc[0][1] += a.x * b.y; acc[0][2] += a.x * b.z; acc[0][3] += a.x * b.w;
            acc[1][0] += a.y * b.x; acc[1][1] += a.y * b.y; acc[1][2] += a.y * b.z; acc[1][3] += a.y * b.w;
            acc[2][0] += a.z * b.x; acc[2][1] += a.z * b.y; acc[2][2] += a.z * b.z; acc[2][3] += a.z * b.w;
            acc[3][0] += a.w * b.x; acc[3][1] += a.w * b.y; acc[3][2] += a.w * b.z; acc[3][3] += a.w * b.w;
        }
    }

    const int row = bm * 64 + (ty << 2);
    const int col = bn * 64 + (tx << 2);
    const float4 bsv = *(const float4*)(bias + col);
    #pragma unroll
    for (int i = 0; i < 4; ++i) {
        float4 o;
        o.x = acc[i][0] + bsv.x; o.y = acc[i][1] + bsv.y;
        o.z = acc[i][2] + bsv.z; o.w = acc[i][3] + bsv.w;
        if (resid) {
            float4 r = *(const float4*)(resid + (size_t)(row + i) * N + col);
            o.x += r.x; o.y += r.y; o.z += r.z; o.w += r.w;
        }
        *(float4*)(C + (size_t)(row + i) * N + col) = o;
    }
}

// ---------------------------------------------------------------------------
// Flash attention (fp32). One block per (b,h, 64-query tile). K/V tiles of 32.
// q,k,v laid out [B*S, D] with head h at columns h*64..h*64+63.
// ---------------------------------------------------------------------------
template<bool CAUSAL>
__global__ __launch_bounds__(256) void attn_kernel(
    const float* __restrict__ Q, const float* __restrict__ K,
    const float* __restrict__ V, float* __restrict__ O)
{
    __shared__ float Qs[64][68];  // [hd][q]  (Q scaled by 1/8)
    __shared__ float Ks[64][36];  // [hd][k]
    __shared__ float Vs[32][68];  // [k][hd]
    __shared__ float Ps[32][68];  // [k][q]

    const int t  = threadIdx.x;
    const int tx = t & 15, ty = t >> 4;
    const int qt = blockIdx.x;
    const int bh = blockIdx.y;
    const int b  = bh >> 4, h = bh & 15;
    const int q0 = qt * 64;

    const float* Qb = Q + (size_t)b * SEQ * D_DIM + h * HDIM;
    const float* Kb = K + (size_t)b * SEQ * D_DIM + h * HDIM;
    const float* Vb = V + (size_t)b * SEQ * D_DIM + h * HDIM;
    float*       Ob = O + (size_t)b * SEQ * D_DIM + h * HDIM;

    // stage Q tile transposed, pre-scaled by 1/sqrt(HD)=0.125
    #pragma unroll
    for (int rep = 0; rep < 4; ++rep) {
        int idx = rep * 256 + t;
        int r = idx >> 4, cq = (idx & 15) << 2;
        float4 qv = *(const float4*)(Qb + (size_t)(q0 + r) * D_DIM + cq);
        Qs[cq + 0][r] = qv.x * 0.125f;
        Qs[cq + 1][r] = qv.y * 0.125f;
        Qs[cq + 2][r] = qv.z * 0.125f;
        Qs[cq + 3][r] = qv.w * 0.125f;
    }

    float o[4][4] = {};
    float m[4] = {-3e38f, -3e38f, -3e38f, -3e38f};
    float l[4] = {};

    const int nkt = CAUSAL ? (q0 / 32 + 2) : (SEQ / 32);

    for (int kt = 0; kt < nkt; ++kt) {
        const int kt0 = kt * 32;
        __syncthreads();
        // stage K (transposed) and V (natural)
        #pragma unroll
        for (int rep = 0; rep < 2; ++rep) {
            int idx = rep * 256 + t;
            int r = idx >> 4, cq = (idx & 15) << 2;
            float4 kv = *(const float4*)(Kb + (size_t)(kt0 + r) * D_DIM + cq);
            Ks[cq + 0][r] = kv.x;
            Ks[cq + 1][r] = kv.y;
            Ks[cq + 2][r] = kv.z;
            Ks[cq + 3][r] = kv.w;
            float4 vv = *(const float4*)(Vb + (size_t)(kt0 + r) * D_DIM + cq);
            *(float4*)&Vs[r][cq] = vv;
        }
        __syncthreads();

        // scores: 4q x 2k per thread, dot over hd=64
        float sc[4][2] = {};
        #pragma unroll 16
        for (int hd = 0; hd < 64; ++hd) {
            float4 qa = *(const float4*)&Qs[hd][ty << 2];
            float2 kb = *(const float2*)&Ks[hd][tx << 1];
            sc[0][0] += qa.x * kb.x; sc[0][1] += qa.x * kb.y;
            sc[1][0] += qa.y * kb.x; sc[1][1] += qa.y * kb.y;
            sc[2][0] += qa.z * kb.x; sc[2][1] += qa.z * kb.y;
            sc[3][0] += qa.w * kb.x; sc[3][1] += qa.w * kb.y;
        }

        if (CAUSAL && (kt0 + 31 > q0)) {
            #pragma unroll
            for (int i = 0; i < 4; ++i)
                #pragma unroll
                for (int j = 0; j < 2; ++j)
                    if (kt0 + (tx << 1) + j > q0 + (ty << 2) + i) sc[i][j] = -1e30f;
        }

        // online softmax (16-lane row groups share a q-row)
        #pragma unroll
        for (int i = 0; i < 4; ++i) {
            float mt = fmaxf(sc[i][0], sc[i][1]);
            #pragma unroll
            for (int off = 1; off < 16; off <<= 1)
                mt = fmaxf(mt, __shfl_xor(mt, off));
            float mnew = fmaxf(m[i], mt);
            float corr = __expf(m[i] - mnew);
            float p0 = __expf(sc[i][0] - mnew);
            float p1 = __expf(sc[i][1] - mnew);
            Ps[(tx << 1) + 0][(ty << 2) + i] = p0;
            Ps[(tx << 1) + 1][(ty << 2) + i] = p1;
            float rs = p0 + p1;
            #pragma unroll
            for (int off = 1; off < 16; off <<= 1)
                rs += __shfl_xor(rs, off);
            l[i] = l[i] * corr + rs;
            m[i] = mnew;
            o[i][0] *= corr; o[i][1] *= corr; o[i][2] *= corr; o[i][3] *= corr;
        }
        __syncthreads();

        // PV: 4q x 4hd per thread over 32 keys
        #pragma unroll 8
        for (int k = 0; k < 32; ++k) {
            float4 pv = *(const float4*)&Ps[k][ty << 2];
            float4 vv = *(const float4*)&Vs[k][tx << 2];
            o[0][0] += pv.x * vv.x; o[0][1] += pv.x * vv.y; o[0][2] += pv.x * vv.z; o[0][3] += pv.x * vv.w;
            o[1][0] += pv.y * vv.x; o[1][1] += pv.y * vv.y; o[1][2] += pv.y * vv.z; o[1][3] += pv.y * vv.w;
            o[2][0] += pv.z * vv.x; o[2][1] += pv.z * vv.y; o[2][2] += pv.z * vv.z; o[2][3] += pv.z * vv.w;
            o[3][0] += pv.w * vv.x; o[3][1] += pv.w * vv.y; o[3][2] += pv.w * vv.z; o[3][3] += pv.w * vv.w;
        }
    }

    const int orow = q0 + (ty << 2);
    const int ocol = tx << 2;
    #pragma unroll
    for (int i = 0; i < 4; ++i) {
        float inv = 1.0f / l[i];
        float4 ov = make_float4(o[i][0] * inv, o[i][1] * inv, o[i][2] * inv, o[i][3] * inv);
        *(float4*)(Ob + (size_t)(orow + i) * D_DIM + ocol) = ov;
    }
}

// ---------------------------------------------------------------------------
// LayerNorm over rows of 1024. One 256-thread block per row.
// ---------------------------------------------------------------------------
__global__ __launch_bounds__(256) void ln_kernel(
    const float* __restrict__ X, const float* __restrict__ g,
    const float* __restrict__ bb, float* __restrict__ out)
{
    const int row = blockIdx.x;
    const int t = threadIdx.x;
    const float* x = X + (size_t)row * D_DIM;
    float4 v = *(const float4*)(x + (t << 2));
    float s  = v.x + v.y + v.z + v.w;
    float sq = v.x * v.x + v.y * v.y + v.z * v.z + v.w * v.w;
    #pragma unroll
    for (int off = 1; off < 64; off <<= 1) {
        s  += __shfl_xor(s, off);
        sq += __shfl_xor(sq, off);
    }
    __shared__ float ss[4], ssq[4];
    const int wid = t >> 6, lane = t & 63;
    if (lane == 0) { ss[wid] = s; ssq[wid] = sq; }
    __syncthreads();
    s  = ss[0] + ss[1] + ss[2] + ss[3];
    sq = ssq[0] + ssq[1] + ssq[2] + ssq[3];
    const float mean = s * (1.0f / 1024.0f);
    const float var  = sq * (1.0f / 1024.0f) - mean * mean;
    const float inv  = rsqrtf(var + 1e-5f);
    float4 gv = *(const float4*)(g  + (t << 2));
    float4 bv = *(const float4*)(bb + (t << 2));
    float4 o;
    o.x = gv.x * (v.x - mean) * inv + bv.x;
    o.y = gv.y * (v.y - mean) * inv + bv.y;
    o.z = gv.z * (v.z - mean) * inv + bv.z;
    o.w = gv.w * (v.w - mean) * inv + bv.w;
    *(float4*)(out + (size_t)row * D_DIM + (t << 2)) = o;
}

// ---------------------------------------------------------------------------
extern "C" void kernel_launch(void* const* d_in, const int* in_sizes, int n_in,
                              void* d_out, int out_size, void* d_ws, size_t ws_size,
                              hipStream_t stream)
{
    (void)in_sizes; (void)n_in; (void)out_size; (void)ws_size;
    const float* S0  = (const float*)d_in[0];
    const float* Hx  = (const float*)d_in[1];
    const float* Wq1 = (const float*)d_in[2];  const float* bq1 = (const float*)d_in[3];
    const float* Wk1 = (const float*)d_in[4];  const float* bk1 = (const float*)d_in[5];
    const float* Wv1 = (const float*)d_in[6];  const float* bv1 = (const float*)d_in[7];
    const float* Wo1 = (const float*)d_in[8];  const float* bo1 = (const float*)d_in[9];
    const float* g1  = (const float*)d_in[10]; const float* b1  = (const float*)d_in[11];
    const float* Wq2 = (const float*)d_in[12]; const float* bq2 = (const float*)d_in[13];
    const float* Wk2 = (const float*)d_in[14]; const float* bk2 = (const float*)d_in[15];
    const float* Wv2 = (const float*)d_in[16]; const float* bv2 = (const float*)d_in[17];
    const float* Wo2 = (const float*)d_in[18]; const float* bo2 = (const float*)d_in[19];
    const float* g2  = (const float*)d_in[20]; const float* b2  = (const float*)d_in[21];
    const float* Wf  = (const float*)d_in[22]; const float* bf  = (const float*)d_in[23];
    const float* g3  = (const float*)d_in[24]; const float* b3  = (const float*)d_in[25];

    float* ws = (float*)d_ws;
    const size_t NE = (size_t)MROWS * D_DIM;   // 4096*1024 floats = 16 MiB
    float* qb = ws + 0 * NE;
    float* kb = ws + 1 * NE;
    float* vb = ws + 2 * NE;
    float* ao = ws + 3 * NE;
    float* tp = ws + 4 * NE;
    float* S1 = ws + 5 * NE;
    float* S2 = ws + 6 * NE;   // total 112 MiB of d_ws

    const dim3 blk(256);
    const dim3 gemm_grid(MROWS / 64, D_DIM / 64);   // 64 x 16
    const dim3 attn_grid(SEQ / 64, 2 * NHEAD);      // 32 x 32
    const dim3 ln_grid(MROWS);

    // ---- layer 1: causal self-attention ----
    gemm_bias_kernel<<<gemm_grid, blk, 0, stream>>>(S0, Wq1, bq1, nullptr, qb);
    gemm_bias_kernel<<<gemm_grid, blk, 0, stream>>>(S0, Wk1, bk1, nullptr, kb);
    gemm_bias_kernel<<<gemm_grid, blk, 0, stream>>>(S0, Wv1, bv1, nullptr, vb);
    attn_kernel<true><<<attn_grid, blk, 0, stream>>>(qb, kb, vb, ao);
    gemm_bias_kernel<<<gemm_grid, blk, 0, stream>>>(ao, Wo1, bo1, S0, tp);
    ln_kernel<<<ln_grid, blk, 0, stream>>>(tp, g1, b1, S1);

    // ---- layer 2: cross-attention over H ----
    gemm_bias_kernel<<<gemm_grid, blk, 0, stream>>>(S1, Wq2, bq2, nullptr, qb);
    gemm_bias_kernel<<<gemm_grid, blk, 0, stream>>>(Hx, Wk2, bk2, nullptr, kb);
    gemm_bias_kernel<<<gemm_grid, blk, 0, stream>>>(Hx, Wv2, bv2, nullptr, vb);
    attn_kernel<false><<<attn_grid, blk, 0, stream>>>(qb, kb, vb, ao);
    gemm_bias_kernel<<<gemm_grid, blk, 0, stream>>>(ao, Wo2, bo2, S1, tp);
    ln_kernel<<<ln_grid, blk, 0, stream>>>(tp, g2, b2, S2);

    // ---- FFN ----
    gemm_bias_kernel<<<gemm_grid, blk, 0, stream>>>(S2, Wf, bf, S2, tp);
    ln_kernel<<<ln_grid, blk, 0, stream>>>(tp, g3, b3, (float*)d_out);
}

// Round 3
// 499.774 us; speedup vs baseline: 5.0015x; 5.0015x over previous
//
#include <hip/hip_runtime.h>
#include <cstdint>
#include <cstddef>

// Decoder cell: B=2, S=T=2048, D=1024, H=16, HD=64.
// bf16 MFMA GEMMs + bf16 MFMA flash attention, fp32 residual stream.
// Round 3: fix causal-mask tile gate (kbase+63 > qw, not qw+31).

#define D_DIM 1024
#define SEQ   2048
#define NHEAD 16
#define HDIM  64
#define MROWS 4096

typedef __attribute__((ext_vector_type(8))) short bf16x8;
typedef __attribute__((ext_vector_type(4))) float f32x4;

static __device__ __forceinline__ short f2bf(float x) {
    union { float f; uint32_t u; } v; v.f = x;
    uint32_t r = (v.u + 0x7fffu + ((v.u >> 16) & 1u)) >> 16;
    return (short)r;
}

#define GLOAD_LDS16(g, l)                                                     \
    __builtin_amdgcn_global_load_lds(                                         \
        (const __attribute__((address_space(1))) unsigned int*)(g),           \
        (__attribute__((address_space(3))) unsigned int*)(l), 16, 0, 0)

// ---------------------------------------------------------------------------
// Weight transpose+convert: W fp32 [1024][1024] -> Wt bf16 [1024][1024] (N,K)
// ---------------------------------------------------------------------------
struct WPtrs { const float* p[9]; };

__global__ __launch_bounds__(256) void transpose_conv_kernel(
    WPtrs wp, short* __restrict__ Wt)
{
    __shared__ float tl[64][65];
    const int t = threadIdx.x;
    const float* src = wp.p[blockIdx.z];
    short* dst = Wt + (size_t)blockIdx.z * D_DIM * D_DIM;
    const int r0 = blockIdx.x * 64;   // k rows in src
    const int c0 = blockIdx.y * 64;   // n cols in src
    #pragma unroll
    for (int i = 0; i < 4; ++i) {
        int row = i * 16 + (t >> 4);
        int col = (t & 15) * 4;
        float4 v = *(const float4*)(src + (size_t)(r0 + row) * D_DIM + c0 + col);
        tl[row][col + 0] = v.x; tl[row][col + 1] = v.y;
        tl[row][col + 2] = v.z; tl[row][col + 3] = v.w;
    }
    __syncthreads();
    #pragma unroll
    for (int i = 0; i < 4; ++i) {
        int nrow = i * 16 + (t >> 4);
        int kcol = (t & 15) * 4;
        ushort4 o;
        o.x = (unsigned short)f2bf(tl[kcol + 0][nrow]);
        o.y = (unsigned short)f2bf(tl[kcol + 1][nrow]);
        o.z = (unsigned short)f2bf(tl[kcol + 2][nrow]);
        o.w = (unsigned short)f2bf(tl[kcol + 3][nrow]);
        *(ushort4*)(dst + (size_t)(c0 + nrow) * D_DIM + r0 + kcol) = o;
    }
}

// ---------------------------------------------------------------------------
// fp32 -> bf16 elementwise (4M elements, 8/thread)
// ---------------------------------------------------------------------------
__global__ __launch_bounds__(256) void conv_kernel(
    const float* __restrict__ src, short* __restrict__ dst)
{
    size_t i = ((size_t)blockIdx.x * 256 + threadIdx.x) * 8;
    float4 a = *(const float4*)(src + i);
    float4 b = *(const float4*)(src + i + 4);
    bf16x8 o;
    o[0] = f2bf(a.x); o[1] = f2bf(a.y); o[2] = f2bf(a.z); o[3] = f2bf(a.w);
    o[4] = f2bf(b.x); o[5] = f2bf(b.y); o[6] = f2bf(b.z); o[7] = f2bf(b.w);
    *(bf16x8*)(dst + i) = o;
}

// ---------------------------------------------------------------------------
// MFMA GEMM: C[M,Nt] = A[M,1024](bf16) @ Wt[Nt,1024]^T + bias (+resid fp32)
// 128x128 tile, BK=32, 4 waves (2x2), 16x16x32 bf16 MFMA (m97 structure).
// ---------------------------------------------------------------------------
template<bool OUT_BF16, bool RESID>
__global__ __launch_bounds__(256) void gemm_mfma_kernel(
    const short* __restrict__ A, const short* __restrict__ Bt,
    const float* __restrict__ bias, const float* __restrict__ resid,
    void* __restrict__ Cout, int ldc, int col0)
{
    __shared__ short As[128 * 32];
    __shared__ short Bs[128 * 32];
    const int t = threadIdx.x;
    const int wave = t >> 6, lane = t & 63;
    const int wm = wave >> 1, wn = wave & 1;
    const int m0 = blockIdx.x * 128, n0 = blockIdx.y * 128;
    const int l15 = lane & 15, l4 = lane >> 4;
    const int lrow = lane >> 2, lcol = (lane & 3) * 8;

    f32x4 acc[4][4] = {};

    for (int k0 = 0; k0 < D_DIM; k0 += 32) {
        __syncthreads();
        #pragma unroll
        for (int c = 0; c < 2; ++c) {
            int chunk = wave + c * 4;            // 0..7
            int row = chunk * 16 + lrow;
            GLOAD_LDS16(A  + (size_t)(m0 + row) * D_DIM + k0 + lcol,
                        As + chunk * 512 + lane * 8);
            GLOAD_LDS16(Bt + (size_t)(n0 + row) * D_DIM + k0 + lcol,
                        Bs + chunk * 512 + lane * 8);
        }
        __syncthreads();

        bf16x8 af[4], bfr[4];
        const int kq = l4 * 8;
        #pragma unroll
        for (int i = 0; i < 4; ++i)
            af[i] = *(const bf16x8*)&As[(wm * 64 + i * 16 + l15) * 32 + kq];
        #pragma unroll
        for (int j = 0; j < 4; ++j)
            bfr[j] = *(const bf16x8*)&Bs[(wn * 64 + j * 16 + l15) * 32 + kq];
        #pragma unroll
        for (int i = 0; i < 4; ++i)
            #pragma unroll
            for (int j = 0; j < 4; ++j)
                acc[i][j] = __builtin_amdgcn_mfma_f32_16x16x32_bf16(
                    af[i], bfr[j], acc[i][j], 0, 0, 0);
    }

    const int rbase = m0 + wm * 64;
    const int cbase = n0 + wn * 64;
    float bv[4];
    #pragma unroll
    for (int j = 0; j < 4; ++j) bv[j] = bias[cbase + j * 16 + l15];

    #pragma unroll
    for (int i = 0; i < 4; ++i) {
        #pragma unroll
        for (int r = 0; r < 4; ++r) {
            const int grow = rbase + i * 16 + l4 * 4 + r;
            #pragma unroll
            for (int j = 0; j < 4; ++j) {
                const int gcol = cbase + j * 16 + l15;
                float v = acc[i][j][r] + bv[j];
                if (RESID) v += resid[(size_t)grow * D_DIM + gcol];
                if (OUT_BF16)
                    ((short*)Cout)[(size_t)grow * ldc + col0 + gcol] = f2bf(v);
                else
                    ((float*)Cout)[(size_t)grow * ldc + col0 + gcol] = v;
            }
        }
    }
}

// ---------------------------------------------------------------------------
// MFMA flash attention. QKV packed [4096][3072] bf16 (q|k|v cols).
// Block: 128 q-rows, 4 waves x 32 rows. KV tiles of 64. Online softmax (exp2).
// ---------------------------------------------------------------------------
template<bool CAUSAL>
__global__ __launch_bounds__(256) void attn_mfma_kernel(
    const short* __restrict__ QKV, short* __restrict__ O)
{
    __shared__ short Ks[64 * 64];       // [k][hd]  swizzled
    __shared__ short Vt[64 * 64];       // [hd][k]  swizzled
    __shared__ short Ps[4][32 * 64];    // per-wave [q][k] swizzled

    const int t = threadIdx.x, wave = t >> 6, lane = t & 63;
    const int qt = blockIdx.x, bh = blockIdx.y, b = bh >> 4, h = bh & 15;
    const int q0 = qt * 128;
    const int l15 = lane & 15, l4 = lane >> 4;
    const size_t rowbase = (size_t)b * SEQ;
    const short* Qp = QKV + rowbase * 3072 + h * HDIM;
    const short* Kp = Qp + 1024;
    const short* Vp = Qp + 2048;
    short* Op = O + rowbase * D_DIM + h * HDIM;

    // Q fragments in registers: wave covers rows qw..qw+31
    const int qw = q0 + wave * 32;
    bf16x8 qf[2][2];
    #pragma unroll
    for (int qs = 0; qs < 2; ++qs)
        #pragma unroll
        for (int kh = 0; kh < 2; ++kh)
            qf[qs][kh] = *(const bf16x8*)(Qp + (size_t)(qw + qs * 16 + l15) * 3072
                                          + kh * 32 + l4 * 8);

    f32x4 oacc[2][4] = {};
    float m_[2][4], l_[2][4];
    #pragma unroll
    for (int qs = 0; qs < 2; ++qs)
        #pragma unroll
        for (int r = 0; r < 4; ++r) { m_[qs][r] = -3e38f; l_[qs][r] = 0.f; }

    const float SC = 0.125f * 1.44269504088896f;   // 1/sqrt(64) * log2(e)
    const int nkt = CAUSAL ? (q0 / 64 + 2) : (SEQ / 64);
    const int srow = t & 63, shd = (t >> 6) * 8;

    for (int kt = 0; kt < nkt; ++kt) {
        const int kbase = kt * 64;
        __syncthreads();
        // stage K [64][64] (row-swizzled) and V transposed [hd][k] (row-swizzled)
        #pragma unroll
        for (int half = 0; half < 2; ++half) {
            const int hh = shd + half * 32;
            bf16x8 kv = *(const bf16x8*)(Kp + (size_t)(kbase + srow) * 3072 + hh);
            *(bf16x8*)&Ks[(srow * 64 + hh) ^ ((srow & 7) << 3)] = kv;
            bf16x8 vv = *(const bf16x8*)(Vp + (size_t)(kbase + srow) * 3072 + hh);
            #pragma unroll
            for (int j = 0; j < 8; ++j) {
                const int hd = hh + j;
                Vt[(hd * 64 + srow) ^ ((hd & 7) << 3)] = vv[j];
            }
        }
        __syncthreads();

        // QK^T: S[32q][64k]
        f32x4 sc[2][4] = {};
        #pragma unroll
        for (int ks = 0; ks < 4; ++ks) {
            const int krow = ks * 16 + l15;
            #pragma unroll
            for (int kh = 0; kh < 2; ++kh) {
                bf16x8 kf = *(const bf16x8*)&Ks[(krow * 64 + kh * 32 + l4 * 8)
                                                ^ ((krow & 7) << 3)];
                sc[0][ks] = __builtin_amdgcn_mfma_f32_16x16x32_bf16(
                    qf[0][kh], kf, sc[0][ks], 0, 0, 0);
                sc[1][ks] = __builtin_amdgcn_mfma_f32_16x16x32_bf16(
                    qf[1][kh], kf, sc[1][ks], 0, 0, 0);
            }
        }
        #pragma unroll
        for (int qs = 0; qs < 2; ++qs)
            #pragma unroll
            for (int ks = 0; ks < 4; ++ks)
                sc[qs][ks] *= SC;

        // FIX (round 3): mask whenever any key in this tile can exceed any row
        // this wave owns (first row qw) — previous gate used qw+31 and skipped
        // masking for waves 1-3 on their diagonal tiles.
        if (CAUSAL && (kbase + 63 > qw)) {
            #pragma unroll
            for (int qs = 0; qs < 2; ++qs)
                #pragma unroll
                for (int ks = 0; ks < 4; ++ks)
                    #pragma unroll
                    for (int r = 0; r < 4; ++r) {
                        const int kc = kbase + ks * 16 + l15;
                        const int qr = qw + qs * 16 + l4 * 4 + r;
                        if (kc > qr) sc[qs][ks][r] = -1e30f;
                    }
        }

        // online softmax, P -> LDS bf16
        #pragma unroll
        for (int qs = 0; qs < 2; ++qs) {
            #pragma unroll
            for (int r = 0; r < 4; ++r) {
                float mt = fmaxf(fmaxf(sc[qs][0][r], sc[qs][1][r]),
                                 fmaxf(sc[qs][2][r], sc[qs][3][r]));
                #pragma unroll
                for (int off = 1; off < 16; off <<= 1)
                    mt = fmaxf(mt, __shfl_xor(mt, off));
                const float mnew = fmaxf(m_[qs][r], mt);
                const float corr = exp2f(m_[qs][r] - mnew);
                float p[4];
                #pragma unroll
                for (int ks = 0; ks < 4; ++ks)
                    p[ks] = exp2f(sc[qs][ks][r] - mnew);
                float rs = (p[0] + p[1]) + (p[2] + p[3]);
                #pragma unroll
                for (int off = 1; off < 16; off <<= 1)
                    rs += __shfl_xor(rs, off);
                l_[qs][r] = l_[qs][r] * corr + rs;
                m_[qs][r] = mnew;
                #pragma unroll
                for (int hds = 0; hds < 4; ++hds) oacc[qs][hds][r] *= corr;
                const int prow = qs * 16 + l4 * 4 + r;
                #pragma unroll
                for (int ks = 0; ks < 4; ++ks)
                    Ps[wave][(prow * 64 + ks * 16 + l15) ^ ((prow & 7) << 3)]
                        = f2bf(p[ks]);
            }
        }

        // PV: O[32q][64hd] += P[32q][64k] @ V[64k][64hd]
        #pragma unroll
        for (int kh = 0; kh < 2; ++kh) {
            bf16x8 pf[2];
            #pragma unroll
            for (int qs = 0; qs < 2; ++qs) {
                const int prow = qs * 16 + l15;
                pf[qs] = *(const bf16x8*)&Ps[wave][(prow * 64 + kh * 32 + l4 * 8)
                                                   ^ ((prow & 7) << 3)];
            }
            #pragma unroll
            for (int hds = 0; hds < 4; ++hds) {
                const int vrow = hds * 16 + l15;
                bf16x8 vf = *(const bf16x8*)&Vt[(vrow * 64 + kh * 32 + l4 * 8)
                                                ^ ((vrow & 7) << 3)];
                oacc[0][hds] = __builtin_amdgcn_mfma_f32_16x16x32_bf16(
                    pf[0], vf, oacc[0][hds], 0, 0, 0);
                oacc[1][hds] = __builtin_amdgcn_mfma_f32_16x16x32_bf16(
                    pf[1], vf, oacc[1][hds], 0, 0, 0);
            }
        }
    }

    #pragma unroll
    for (int qs = 0; qs < 2; ++qs)
        #pragma unroll
        for (int r = 0; r < 4; ++r) {
            const float inv = 1.0f / l_[qs][r];
            const int grow = qw + qs * 16 + l4 * 4 + r;
            #pragma unroll
            for (int hds = 0; hds < 4; ++hds)
                Op[(size_t)grow * D_DIM + hds * 16 + l15]
                    = f2bf(oacc[qs][hds][r] * inv);
        }
}

// ---------------------------------------------------------------------------
// LayerNorm rows of 1024; optional bf16 side output. In-place safe.
// ---------------------------------------------------------------------------
__global__ __launch_bounds__(256) void ln_kernel(
    const float* __restrict__ X, const float* __restrict__ g,
    const float* __restrict__ bb, float* __restrict__ outf,
    short* __restrict__ outb)
{
    const int row = blockIdx.x;
    const int t = threadIdx.x;
    const float* x = X + (size_t)row * D_DIM;
    float4 v = *(const float4*)(x + (t << 2));
    float s  = v.x + v.y + v.z + v.w;
    float sq = v.x * v.x + v.y * v.y + v.z * v.z + v.w * v.w;
    #pragma unroll
    for (int off = 1; off < 64; off <<= 1) {
        s  += __shfl_xor(s, off);
        sq += __shfl_xor(sq, off);
    }
    __shared__ float ss[4], ssq[4];
    const int wid = t >> 6, lane = t & 63;
    if (lane == 0) { ss[wid] = s; ssq[wid] = sq; }
    __syncthreads();
    s  = ss[0] + ss[1] + ss[2] + ss[3];
    sq = ssq[0] + ssq[1] + ssq[2] + ssq[3];
    const float mean = s * (1.0f / 1024.0f);
    const float var  = sq * (1.0f / 1024.0f) - mean * mean;
    const float inv  = rsqrtf(var + 1e-5f);
    float4 gv = *(const float4*)(g  + (t << 2));
    float4 bv = *(const float4*)(bb + (t << 2));
    float4 o;
    o.x = gv.x * (v.x - mean) * inv + bv.x;
    o.y = gv.y * (v.y - mean) * inv + bv.y;
    o.z = gv.z * (v.z - mean) * inv + bv.z;
    o.w = gv.w * (v.w - mean) * inv + bv.w;
    if (outf) *(float4*)(outf + (size_t)row * D_DIM + (t << 2)) = o;
    if (outb) {
        ushort4 ob;
        ob.x = (unsigned short)f2bf(o.x); ob.y = (unsigned short)f2bf(o.y);
        ob.z = (unsigned short)f2bf(o.z); ob.w = (unsigned short)f2bf(o.w);
        *(ushort4*)(outb + (size_t)row * D_DIM + (t << 2)) = ob;
    }
}

// ---------------------------------------------------------------------------
extern "C" void kernel_launch(void* const* d_in, const int* in_sizes, int n_in,
                              void* d_out, int out_size, void* d_ws, size_t ws_size,
                              hipStream_t stream)
{
    (void)in_sizes; (void)n_in; (void)out_size; (void)ws_size;
    const float* S0f = (const float*)d_in[0];
    const float* Hf  = (const float*)d_in[1];
    const float* bq1 = (const float*)d_in[3];
    const float* bk1 = (const float*)d_in[5];
    const float* bv1 = (const float*)d_in[7];
    const float* bo1 = (const float*)d_in[9];
    const float* g1  = (const float*)d_in[10]; const float* b1 = (const float*)d_in[11];
    const float* bq2 = (const float*)d_in[13];
    const float* bk2 = (const float*)d_in[15];
    const float* bv2 = (const float*)d_in[17];
    const float* bo2 = (const float*)d_in[19];
    const float* g2  = (const float*)d_in[20]; const float* b2 = (const float*)d_in[21];
    const float* bff = (const float*)d_in[23];
    const float* g3  = (const float*)d_in[24]; const float* b3 = (const float*)d_in[25];

    char* ws = (char*)d_ws;
    size_t off = 0;
    auto alloc = [&](size_t bytes) { char* p = ws + off; off += (bytes + 255) & ~(size_t)255; return p; };
    short* Wt   = (short*)alloc((size_t)9 * D_DIM * D_DIM * 2);   // 18 MB
    short* bS0  = (short*)alloc((size_t)MROWS * D_DIM * 2);       // 8 MB
    short* bH   = (short*)alloc((size_t)MROWS * D_DIM * 2);       // 8 MB
    short* bQKV = (short*)alloc((size_t)MROWS * 3072 * 2);        // 24 MB
    short* bAO  = (short*)alloc((size_t)MROWS * D_DIM * 2);       // 8 MB
    float* X    = (float*)alloc((size_t)MROWS * D_DIM * 4);       // 16 MB
    short* bSx  = (short*)alloc((size_t)MROWS * D_DIM * 2);       // 8 MB
    float* cb1  = (float*)alloc(3072 * 4);
    float* cb2  = (float*)alloc(2048 * 4);

    const size_t WSTRIDE = (size_t)D_DIM * D_DIM;   // shorts per weight

    // weight transposes (9 at once)
    WPtrs wp;
    wp.p[0] = (const float*)d_in[2];   // Wq1
    wp.p[1] = (const float*)d_in[4];   // Wk1
    wp.p[2] = (const float*)d_in[6];   // Wv1
    wp.p[3] = (const float*)d_in[8];   // Wo1
    wp.p[4] = (const float*)d_in[12];  // Wq2
    wp.p[5] = (const float*)d_in[14];  // Wk2
    wp.p[6] = (const float*)d_in[16];  // Wv2
    wp.p[7] = (const float*)d_in[18];  // Wo2
    wp.p[8] = (const float*)d_in[22];  // Wf
    transpose_conv_kernel<<<dim3(16, 16, 9), 256, 0, stream>>>(wp, Wt);

    // activation conversions
    conv_kernel<<<2048, 256, 0, stream>>>(S0f, bS0);
    conv_kernel<<<2048, 256, 0, stream>>>(Hf, bH);

    // concatenated bias vectors
    hipMemcpyAsync(cb1,        bq1, 4096, hipMemcpyDeviceToDevice, stream);
    hipMemcpyAsync(cb1 + 1024, bk1, 4096, hipMemcpyDeviceToDevice, stream);
    hipMemcpyAsync(cb1 + 2048, bv1, 4096, hipMemcpyDeviceToDevice, stream);
    hipMemcpyAsync(cb2,        bk2, 4096, hipMemcpyDeviceToDevice, stream);
    hipMemcpyAsync(cb2 + 1024, bv2, 4096, hipMemcpyDeviceToDevice, stream);

    const dim3 blk(256);

    // ---- layer 1: causal self-attention ----
    gemm_mfma_kernel<true, false><<<dim3(32, 24), blk, 0, stream>>>(
        bS0, Wt, cb1, nullptr, bQKV, 3072, 0);
    attn_mfma_kernel<true><<<dim3(16, 32), blk, 0, stream>>>(bQKV, bAO);
    gemm_mfma_kernel<false, true><<<dim3(32, 8), blk, 0, stream>>>(
        bAO, Wt + 3 * WSTRIDE, bo1, S0f, X, 1024, 0);
    ln_kernel<<<MROWS, blk, 0, stream>>>(X, g1, b1, X, bSx);

    // ---- layer 2: cross-attention over H ----
    gemm_mfma_kernel<true, false><<<dim3(32, 8), blk, 0, stream>>>(
        bSx, Wt + 4 * WSTRIDE, bq2, nullptr, bQKV, 3072, 0);
    gemm_mfma_kernel<true, false><<<dim3(32, 16), blk, 0, stream>>>(
        bH, Wt + 5 * WSTRIDE, cb2, nullptr, bQKV, 3072, 1024);
    attn_mfma_kernel<false><<<dim3(16, 32), blk, 0, stream>>>(bQKV, bAO);
    gemm_mfma_kernel<false, true><<<dim3(32, 8), blk, 0, stream>>>(
        bAO, Wt + 7 * WSTRIDE, bo2, X, X, 1024, 0);
    ln_kernel<<<MROWS, blk, 0, stream>>>(X, g2, b2, X, bSx);

    // ---- FFN ----
    gemm_mfma_kernel<false, true><<<dim3(32, 8), blk, 0, stream>>>(
        bSx, Wt + 8 * WSTRIDE, bff, X, X, 1024, 0);
    ln_kernel<<<MROWS, blk, 0, stream>>>(X, g3, b3, (float*)d_out, nullptr);
}